// Round 2
// baseline (274.312 us; speedup 1.0000x reference)
//
#include <hip/hip_runtime.h>
#include <hip/hip_bf16.h>

#define NN 1024
#define DD 128
#define TS 64          // gram tile edge
#define PITCH 136      // bf16 elems per LDS feat row (128 + 8 pad)
#define SQP 68         // f32 elems per LDS G row (64 + 4 pad)

// ws layout (floats)
#define WS_COORD 0
#define WS_REG   1
#define WS_BCE   2
#define WS_POSN  3     // [3,19)   per-batch  sum A*(ni+nj)
#define WS_POSC  19    // [19,35)  per-batch  count A>0.5
#define WS_NEGS  35    // [35,51)  per-batch  hinge^2 sum (rare)
#define WS_PDIAG 51    // [51,67)  per-batch  diag positives
#define WS_CROSS 67    // [67,83)  per-batch  sum A*G
#define WS_CNT   83    // [83,99)  per-batch  mask sums
#define WS_NORM  112   // [112, 112+16384) node norms n[b][i] (f32)

typedef __bf16 bf16_t;
typedef bf16_t bf16x8 __attribute__((ext_vector_type(8)));
typedef float  f32x4  __attribute__((ext_vector_type(4)));

// ---------------- kernel 0: norms + reg + coord + mask counts ----------------
__global__ __launch_bounds__(256) void prep(
    const float* __restrict__ feat, const float* __restrict__ pcoord,
    const float* __restrict__ pts,  const float* __restrict__ masks,
    float* __restrict__ ws) {
  __shared__ float red[4][3];
  const int bx = blockIdx.x;               // 128 blocks: 8 per batch
  const int b = bx >> 3, slab = bx & 7;
  const int t = threadIdx.x, lane = t & 63, w = t >> 6;
  const int sub = lane >> 4, lq = lane & 15;   // 4 nodes per wave, 16 lanes/node
  const float* fb = feat + (size_t)b * NN * DD;

  float reg = 0.f;
  #pragma unroll
  for (int it = 0; it < 8; ++it) {
    const int node = slab * 128 + it * 16 + w * 4 + sub;
    const float4* src = (const float4*)(fb + (size_t)node * DD) + lq * 2;
    float4 u = src[0], v = src[1];
    float s = u.x*u.x + u.y*u.y + u.z*u.z + u.w*u.w
            + v.x*v.x + v.y*v.y + v.z*v.z + v.w*v.w;
    s += __shfl_xor(s, 1); s += __shfl_xor(s, 2);
    s += __shfl_xor(s, 4); s += __shfl_xor(s, 8);
    if (lq == 0) { ws[WS_NORM + b * NN + node] = s; reg += s; }
  }
  // coord: one scalar element per thread (128*256 = 32768 = 16*1024*2)
  const int ci = bx * 256 + t;
  const float d = pcoord[ci] - pts[ci];
  float coord = d * d;
  // mask slab sum (128 floats per block)
  float cnt = (t < 128) ? masks[b * NN + slab * 128 + t] : 0.f;

  #pragma unroll
  for (int o = 32; o; o >>= 1) {
    coord += __shfl_xor(coord, o);
    reg   += __shfl_xor(reg, o);
    cnt   += __shfl_xor(cnt, o);
  }
  if (lane == 0) { red[w][0] = coord; red[w][1] = reg; red[w][2] = cnt; }
  __syncthreads();
  if (t == 0) {
    float c = 0.f, r = 0.f, n = 0.f;
    for (int i = 0; i < 4; ++i) { c += red[i][0]; r += red[i][1]; n += red[i][2]; }
    atomicAdd(&ws[WS_COORD], c);
    atomicAdd(&ws[WS_REG], r);
    atomicAdd(&ws[WS_CNT + b], n);
  }
}

// ---------------- kernel 1: pure stream of logits+adj ----------------
// 2048 blocks x 256 threads = 8 blocks/CU, all resident. Block = 8 rows of one
// batch; thread t owns columns 4t..4t+3 for every row -> n_j in 4 registers.
__global__ __launch_bounds__(256, 8) void stream_bce(
    const float* __restrict__ logits, const float* __restrict__ adj,
    float* __restrict__ ws) {
  __shared__ float red[4][4];
  const int bx = blockIdx.x;               // 2048
  const int b = bx >> 7, rblk = bx & 127;
  const int t = threadIdx.x, lane = t & 63, w = t >> 6;
  const size_t base = ((size_t)b * NN + (size_t)rblk * 8) * NN;
  const float4* Lr = (const float4*)(logits + base);
  const float4* Ar = (const float4*)(adj + base);
  const float* nrm = ws + WS_NORM + b * NN;
  const float4 nj = *(const float4*)(nrm + t * 4);

  float bce = 0.f, posc = 0.f, posn = 0.f, pdiag = 0.f;
  #pragma unroll 4
  for (int r = 0; r < 8; ++r) {
    const int grow = rblk * 8 + r;
    const float ni = nrm[grow];
    const float4 L = Lr[r * 256 + t];
    const float4 A = Ar[r * 256 + t];
    bce += fmaxf(L.x, 0.f) - L.x * A.x + __logf(1.f + __expf(-fabsf(L.x)));
    bce += fmaxf(L.y, 0.f) - L.y * A.y + __logf(1.f + __expf(-fabsf(L.y)));
    bce += fmaxf(L.z, 0.f) - L.z * A.z + __logf(1.f + __expf(-fabsf(L.z)));
    bce += fmaxf(L.w, 0.f) - L.w * A.w + __logf(1.f + __expf(-fabsf(L.w)));
    const float px = (A.x > 0.5f) ? 1.f : 0.f;
    const float py = (A.y > 0.5f) ? 1.f : 0.f;
    const float pz = (A.z > 0.5f) ? 1.f : 0.f;
    const float pw = (A.w > 0.5f) ? 1.f : 0.f;
    posc += px + py + pz + pw;
    posn += px * (ni + nj.x) + py * (ni + nj.y)
          + pz * (ni + nj.z) + pw * (ni + nj.w);
    if ((grow >> 2) == t) {                // diagonal element lives in this thread
      const int e = grow & 3;
      const float av = (e == 0) ? A.x : (e == 1) ? A.y : (e == 2) ? A.z : A.w;
      if (av > 0.5f) pdiag += 1.f;
    }
  }
  #pragma unroll
  for (int o = 32; o; o >>= 1) {
    bce  += __shfl_xor(bce, o);
    posc += __shfl_xor(posc, o);
    posn += __shfl_xor(posn, o);
    pdiag += __shfl_xor(pdiag, o);
  }
  if (lane == 0) { red[w][0] = bce; red[w][1] = posc; red[w][2] = posn; red[w][3] = pdiag; }
  __syncthreads();
  if (t == 0) {
    float s0 = 0.f, s1 = 0.f, s2 = 0.f, s3 = 0.f;
    for (int i = 0; i < 4; ++i) { s0 += red[i][0]; s1 += red[i][1]; s2 += red[i][2]; s3 += red[i][3]; }
    atomicAdd(&ws[WS_BCE], s0);
    atomicAdd(&ws[WS_POSC + b], s1);
    atomicAdd(&ws[WS_POSN + b], s2);
    atomicAdd(&ws[WS_PDIAG + b], s3);
  }
}

// ---------------- kernel 2: Gram sweep: cross = sum A*G, neg safety ----------------
__device__ __forceinline__ void ce(float a, float g, float ni, float njv,
                                   int grow, int gcol, float& cross, float& negs) {
  if (a > 0.5f) {
    cross += g;
  } else {
    const float sq = ni + njv - 2.f * g;
    if (sq < 1.f && grow != gcol) {        // essentially never for these inputs
      const float dd = sqrtf(fmaxf(sq, 1e-12f));
      const float h = 1.f - dd;
      negs += h * h;
    }
  }
}

__global__ __launch_bounds__(256, 4) void gram_tiles(
    const float* __restrict__ adj, const float* __restrict__ feat,
    float* __restrict__ ws) {
  __shared__ __align__(16) char smem[2 * TS * PITCH * sizeof(bf16_t)];  // 34816 B
  bf16_t* lsA = (bf16_t*)smem;
  bf16_t* lsB = (bf16_t*)(smem + TS * PITCH * sizeof(bf16_t));
  float*  gbuf = (float*)smem;            // overlays lsA: 64*68*4 = 17408 B
  __shared__ float red[4][2];

  const int bx = blockIdx.x;              // 4096
  const int bm = ((bx & 7) << 9) | (bx >> 3);   // XCD swizzle: 512 blocks/XCD = 2 batches
  const int b = bm >> 8, tid = bm & 255;
  const int ti = (tid >> 4) << 6, tj = (tid & 15) << 6;
  const int t = threadIdx.x, lane = t & 63, wave = t >> 6;
  const int lrow = lane & 15, quad = lane >> 4;
  const int r0 = t >> 4, c4 = t & 15;
  const float* fb = feat + (size_t)b * NN * DD;

  // stage feat tiles (A rows [ti,ti+64), B rows [tj,tj+64)) as bf16
  #pragma unroll
  for (int it = 0; it < 8; ++it) {
    const int cid = it * 256 + t;
    const int tile = cid >> 10;
    const int sub = cid & 1023;
    const int row = sub >> 4;
    const int c8 = sub & 15;
    const float* src = fb + (size_t)((tile ? tj : ti) + row) * DD + c8 * 8;
    const float4 u = *(const float4*)src;
    const float4 v = *(const float4*)(src + 4);
    bf16x8 pk;
    pk[0]=(bf16_t)u.x; pk[1]=(bf16_t)u.y; pk[2]=(bf16_t)u.z; pk[3]=(bf16_t)u.w;
    pk[4]=(bf16_t)v.x; pk[5]=(bf16_t)v.y; pk[6]=(bf16_t)v.z; pk[7]=(bf16_t)v.w;
    *(bf16x8*)((tile ? lsB : lsA) + row * PITCH + c8 * 8) = pk;
  }
  __syncthreads();

  // A-tile prefetch (row-major float4, mostly L3-hot second pass)
  const float* ap = adj + (size_t)b * NN * NN + (size_t)(ti + r0) * NN + (tj + c4 * 4);
  float4 Ab[4];
  #pragma unroll
  for (int it = 0; it < 4; ++it) Ab[it] = *(const float4*)(ap + (size_t)it * 16 * NN);

  // MFMA Gram: wave w rows [w*16,w*16+16) x 64 cols
  f32x4 acc[4];
  #pragma unroll
  for (int fc = 0; fc < 4; ++fc) acc[fc] = (f32x4){0.f, 0.f, 0.f, 0.f};
  #pragma unroll
  for (int k0 = 0; k0 < DD; k0 += 32) {
    const int kc = k0 + quad * 8;
    const bf16x8 aF = *(const bf16x8*)&lsA[(wave * 16 + lrow) * PITCH + kc];
    #pragma unroll
    for (int fc = 0; fc < 4; ++fc) {
      const bf16x8 bF = *(const bf16x8*)&lsB[(fc * 16 + lrow) * PITCH + kc];
      acc[fc] = __builtin_amdgcn_mfma_f32_16x16x32_bf16(aF, bF, acc[fc], 0, 0, 0);
    }
  }
  __syncthreads();

  // G fragment -> LDS (row = wave*16+quad*4+r, col = fc*16+lrow)
  {
    const int rbase = wave * 16 + quad * 4;
    #pragma unroll
    for (int fc = 0; fc < 4; ++fc) {
      const int ctile = fc * 16 + lrow;
      #pragma unroll
      for (int r = 0; r < 4; ++r)
        gbuf[(rbase + r) * SQP + ctile] = acc[fc][r];
    }
  }
  __syncthreads();

  // consume in row layout, norms from ws
  const float* nrm = ws + WS_NORM + b * NN;
  const float4 nj = *(const float4*)(nrm + tj + c4 * 4);
  float cross = 0.f, negs = 0.f;
  #pragma unroll
  for (int it = 0; it < 4; ++it) {
    const int row = it * 16 + r0;
    const int grow = ti + row;
    const float ni = nrm[grow];
    const float4 g = *(const float4*)&gbuf[row * SQP + c4 * 4];
    const float4 A = Ab[it];
    const int gc = tj + c4 * 4;
    ce(A.x, g.x, ni, nj.x, grow, gc + 0, cross, negs);
    ce(A.y, g.y, ni, nj.y, grow, gc + 1, cross, negs);
    ce(A.z, g.z, ni, nj.z, grow, gc + 2, cross, negs);
    ce(A.w, g.w, ni, nj.w, grow, gc + 3, cross, negs);
  }
  #pragma unroll
  for (int o = 32; o; o >>= 1) {
    cross += __shfl_xor(cross, o);
    negs  += __shfl_xor(negs, o);
  }
  if (lane == 0) { red[wave][0] = cross; red[wave][1] = negs; }
  __syncthreads();
  if (t == 0) {
    float s0 = 0.f, s1 = 0.f;
    for (int i = 0; i < 4; ++i) { s0 += red[i][0]; s1 += red[i][1]; }
    atomicAdd(&ws[WS_CROSS + b], s0);
    atomicAdd(&ws[WS_NEGS + b], s1);
  }
}

// ---------------- finalize ----------------
__global__ void finalize(const float* __restrict__ ws, const float* __restrict__ pcount,
                         float* __restrict__ out) {
  if (threadIdx.x != 0 || blockIdx.x != 0) return;
  const float coord = ws[WS_COORD] / 32768.f;
  const float reg   = ws[WS_REG] / 2097152.f;
  const float edge  = ws[WS_BCE] / 16777216.f;
  float cntl = 0.f, contra = 0.f;
  for (int b = 0; b < 16; ++b) {
    const float d = fabsf(pcount[b] - ws[WS_CNT + b]);
    cntl += (d < 1.f) ? 0.5f * d * d : d - 0.5f;
    const float posc = ws[WS_POSC + b];
    const float pos = (ws[WS_POSN + b] - 2.f * ws[WS_CROSS + b]) / fmaxf(posc, 1.f);
    const float negc = 1024.f * 1024.f - 1024.f - (posc - ws[WS_PDIAG + b]);
    const float neg = ws[WS_NEGS + b] / fmaxf(negc, 1.f);
    contra += pos + neg;
  }
  cntl *= (1.f / 16.f);
  contra *= (1.f / 16.f);
  const float total = coord + 2.f * edge + 0.1f * cntl + 0.001f * reg + 0.1f * contra;
  out[0] = total; out[1] = coord; out[2] = edge;
  out[3] = cntl;  out[4] = reg;   out[5] = contra;
}

extern "C" void kernel_launch(void* const* d_in, const int* in_sizes, int n_in,
                              void* d_out, int out_size, void* d_ws, size_t ws_size,
                              hipStream_t stream) {
  (void)in_sizes; (void)n_in; (void)out_size; (void)ws_size;
  const float* pcoord = (const float*)d_in[0];
  const float* pts    = (const float*)d_in[1];
  const float* logits = (const float*)d_in[2];
  const float* adj    = (const float*)d_in[3];
  const float* masks  = (const float*)d_in[4];
  const float* pcount = (const float*)d_in[5];
  const float* nf     = (const float*)d_in[6];
  float* ws  = (float*)d_ws;
  float* out = (float*)d_out;

  hipMemsetAsync(ws, 0, WS_NORM * sizeof(float), stream);
  prep<<<128, 256, 0, stream>>>(nf, pcoord, pts, masks, ws);
  stream_bce<<<2048, 256, 0, stream>>>(logits, adj, ws);
  gram_tiles<<<4096, 256, 0, stream>>>(adj, nf, ws);
  finalize<<<1, 64, 0, stream>>>(ws, pcount, out);
}

// Round 3
// 270.587 us; speedup vs baseline: 1.0138x; 1.0138x over previous
//
#include <hip/hip_runtime.h>
#include <hip/hip_bf16.h>

#define NN 1024
#define DD 128
#define TS 64          // gram tile edge
#define PITCH 136      // bf16 elems per LDS feat row (128 + 8 pad)
#define SQP 68         // f32 elems per LDS G row (64 + 4 pad)

// ws layout (floats)
#define WS_COORD 0
#define WS_REG   1
#define WS_BCE   2
#define WS_POSN  3     // [3,19)   per-batch  sum A*(ni+nj)
#define WS_POSC  19    // [19,35)  per-batch  count A>0.5
#define WS_NEGS  35    // [35,51)  per-batch  hinge^2 sum (rare)
#define WS_PDIAG 51    // [51,67)  per-batch  diag positives
#define WS_CROSS 67    // [67,83)  per-batch  sum A*G
#define WS_CNT   83    // [83,99)  per-batch  mask sums
#define WS_NORM  112   // [112, 112+16384) node norms n[b][i] (f32)

typedef __bf16 bf16_t;
typedef bf16_t bf16x8 __attribute__((ext_vector_type(8)));
typedef float  f32x4  __attribute__((ext_vector_type(4)));

// ---------------- kernel 0: norms + reg + coord + mask counts ----------------
__global__ __launch_bounds__(256) void prep(
    const float* __restrict__ feat, const float* __restrict__ pcoord,
    const float* __restrict__ pts,  const float* __restrict__ masks,
    float* __restrict__ ws) {
  __shared__ float red[4][3];
  const int bx = blockIdx.x;               // 128 blocks: 8 per batch
  const int b = bx >> 3, slab = bx & 7;
  const int t = threadIdx.x, lane = t & 63, w = t >> 6;
  const int sub = lane >> 4, lq = lane & 15;   // 4 nodes per wave, 16 lanes/node
  const float* fb = feat + (size_t)b * NN * DD;

  float reg = 0.f;
  #pragma unroll
  for (int it = 0; it < 8; ++it) {
    const int node = slab * 128 + it * 16 + w * 4 + sub;
    const float4* src = (const float4*)(fb + (size_t)node * DD) + lq * 2;
    float4 u = src[0], v = src[1];
    float s = u.x*u.x + u.y*u.y + u.z*u.z + u.w*u.w
            + v.x*v.x + v.y*v.y + v.z*v.z + v.w*v.w;
    s += __shfl_xor(s, 1); s += __shfl_xor(s, 2);
    s += __shfl_xor(s, 4); s += __shfl_xor(s, 8);
    if (lq == 0) { ws[WS_NORM + b * NN + node] = s; reg += s; }
  }
  // coord: one scalar element per thread (128*256 = 32768 = 16*1024*2)
  const int ci = bx * 256 + t;
  const float d = pcoord[ci] - pts[ci];
  float coord = d * d;
  // mask slab sum (128 floats per block)
  float cnt = (t < 128) ? masks[b * NN + slab * 128 + t] : 0.f;

  #pragma unroll
  for (int o = 32; o; o >>= 1) {
    coord += __shfl_xor(coord, o);
    reg   += __shfl_xor(reg, o);
    cnt   += __shfl_xor(cnt, o);
  }
  if (lane == 0) { red[w][0] = coord; red[w][1] = reg; red[w][2] = cnt; }
  __syncthreads();
  if (t == 0) {
    float c = 0.f, r = 0.f, n = 0.f;
    for (int i = 0; i < 4; ++i) { c += red[i][0]; r += red[i][1]; n += red[i][2]; }
    atomicAdd(&ws[WS_COORD], c);
    atomicAdd(&ws[WS_REG], r);
    atomicAdd(&ws[WS_CNT + b], n);
  }
}

// ---------------- kernel 1: fused tile: BCE stream + Gram cross ----------------
__device__ __forceinline__ void elem(float l, float a, float g, float ni, float njv,
    int grow, int gcol, float& bce, float& posc, float& posn, float& pdiag,
    float& cross, float& negs) {
  bce += fmaxf(l, 0.f) - l * a + __logf(1.f + __expf(-fabsf(l)));
  if (a > 0.5f) {
    posc += 1.f; posn += ni + njv; cross += g;
    if (grow == gcol) pdiag += 1.f;
  } else if (grow != gcol) {
    const float sq = ni + njv - 2.f * g;
    if (sq < 1.f) {                        // essentially never for these inputs
      const float d = sqrtf(fmaxf(sq, 1e-12f));
      const float h = 1.f - d;
      negs += h * h;
    }
  }
}

__global__ __launch_bounds__(256, 4) void fused_tiles(
    const float* __restrict__ logits, const float* __restrict__ adj,
    const float* __restrict__ feat, float* __restrict__ ws) {
  __shared__ __align__(16) char smem[2 * TS * PITCH * sizeof(bf16_t)];  // 34816 B
  bf16_t* lsA = (bf16_t*)smem;
  bf16_t* lsB = (bf16_t*)(smem + TS * PITCH * sizeof(bf16_t));
  float*  gbuf = (float*)smem;            // overlays lsA exactly: 64*68*4 = 17408 B
  __shared__ float red[4][6];

  const int bx = blockIdx.x;              // 4096
  const int bm = ((bx & 7) << 9) | (bx >> 3);   // XCD swizzle: 512 blocks = 2 batches/XCD
  const int b = bm >> 8, tid = bm & 255;
  const int ti = (tid >> 4) << 6, tj = (tid & 15) << 6;
  const int t = threadIdx.x, lane = t & 63, wave = t >> 6;
  const int lrow = lane & 15, quad = lane >> 4;
  const int r0 = t >> 4, c4 = t & 15;     // consume layout: 16 rows x 16 float4-cols
  const float* fb = feat + (size_t)b * NN * DD;

  // ---- issue the HBM-latency loads FIRST: 8 float4 of L/A + norms ----
  const size_t abase = (size_t)b * NN * NN + (size_t)(ti + r0) * NN + (tj + c4 * 4);
  const float* lp = logits + abase;
  const float* ap = adj + abase;
  float4 Lb[4], Ab[4];
  #pragma unroll
  for (int it = 0; it < 4; ++it) {
    Lb[it] = *(const float4*)(lp + (size_t)it * 16 * NN);
    Ab[it] = *(const float4*)(ap + (size_t)it * 16 * NN);
  }
  const float* nrm = ws + WS_NORM + b * NN;
  const float4 njv = *(const float4*)(nrm + tj + c4 * 4);
  float niv[4];
  #pragma unroll
  for (int it = 0; it < 4; ++it) niv[it] = nrm[ti + it * 16 + r0];

  // ---- stage feat tiles (A rows [ti,ti+64), B rows [tj,tj+64)) as bf16; L2-hot ----
  #pragma unroll
  for (int it = 0; it < 8; ++it) {
    const int cid = it * 256 + t;
    const int tile = cid >> 10;
    const int sub = cid & 1023;
    const int row = sub >> 4;
    const int c8 = sub & 15;
    const float* src = fb + (size_t)((tile ? tj : ti) + row) * DD + c8 * 8;
    const float4 u = *(const float4*)src;
    const float4 v = *(const float4*)(src + 4);
    bf16x8 pk;
    pk[0]=(bf16_t)u.x; pk[1]=(bf16_t)u.y; pk[2]=(bf16_t)u.z; pk[3]=(bf16_t)u.w;
    pk[4]=(bf16_t)v.x; pk[5]=(bf16_t)v.y; pk[6]=(bf16_t)v.z; pk[7]=(bf16_t)v.w;
    *(bf16x8*)((tile ? lsB : lsA) + row * PITCH + c8 * 8) = pk;
  }
  __syncthreads();

  // ---- MFMA Gram: wave w rows [w*16,w*16+16) x 64 cols (L/A loads in flight) ----
  f32x4 acc[4];
  #pragma unroll
  for (int fc = 0; fc < 4; ++fc) acc[fc] = (f32x4){0.f, 0.f, 0.f, 0.f};
  #pragma unroll
  for (int k0 = 0; k0 < DD; k0 += 32) {
    const int kc = k0 + quad * 8;
    const bf16x8 aF = *(const bf16x8*)&lsA[(wave * 16 + lrow) * PITCH + kc];
    #pragma unroll
    for (int fc = 0; fc < 4; ++fc) {
      const bf16x8 bF = *(const bf16x8*)&lsB[(fc * 16 + lrow) * PITCH + kc];
      acc[fc] = __builtin_amdgcn_mfma_f32_16x16x32_bf16(aF, bF, acc[fc], 0, 0, 0);
    }
  }
  __syncthreads();

  // ---- G fragment -> LDS (row = wave*16+quad*4+r, col = fc*16+lrow) ----
  {
    const int rbase = wave * 16 + quad * 4;
    #pragma unroll
    for (int fc = 0; fc < 4; ++fc) {
      const int ctile = fc * 16 + lrow;
      #pragma unroll
      for (int r = 0; r < 4; ++r)
        gbuf[(rbase + r) * SQP + ctile] = acc[fc][r];
    }
  }
  __syncthreads();

  // ---- consume in row layout: BCE + pos algebra + neg safety ----
  float bce = 0.f, posc = 0.f, posn = 0.f, pdiag = 0.f, cross = 0.f, negs = 0.f;
  #pragma unroll
  for (int it = 0; it < 4; ++it) {
    const int row = it * 16 + r0;
    const int grow = ti + row;
    const int gc = tj + c4 * 4;
    const float4 g = *(const float4*)&gbuf[row * SQP + c4 * 4];
    const float4 L = Lb[it];
    const float4 A = Ab[it];
    const float ni = niv[it];
    elem(L.x, A.x, g.x, ni, njv.x, grow, gc + 0, bce, posc, posn, pdiag, cross, negs);
    elem(L.y, A.y, g.y, ni, njv.y, grow, gc + 1, bce, posc, posn, pdiag, cross, negs);
    elem(L.z, A.z, g.z, ni, njv.z, grow, gc + 2, bce, posc, posn, pdiag, cross, negs);
    elem(L.w, A.w, g.w, ni, njv.w, grow, gc + 3, bce, posc, posn, pdiag, cross, negs);
  }

  // ---- block reduction (6 values) + per-batch atomics ----
  #pragma unroll
  for (int o = 32; o; o >>= 1) {
    bce   += __shfl_xor(bce, o);
    posc  += __shfl_xor(posc, o);
    posn  += __shfl_xor(posn, o);
    pdiag += __shfl_xor(pdiag, o);
    cross += __shfl_xor(cross, o);
    negs  += __shfl_xor(negs, o);
  }
  if (lane == 0) {
    red[wave][0] = bce;   red[wave][1] = posc; red[wave][2] = posn;
    red[wave][3] = pdiag; red[wave][4] = cross; red[wave][5] = negs;
  }
  __syncthreads();
  if (t == 0) {
    float s0=0.f,s1=0.f,s2=0.f,s3=0.f,s4=0.f,s5=0.f;
    for (int i = 0; i < 4; ++i) {
      s0 += red[i][0]; s1 += red[i][1]; s2 += red[i][2];
      s3 += red[i][3]; s4 += red[i][4]; s5 += red[i][5];
    }
    atomicAdd(&ws[WS_BCE], s0);
    atomicAdd(&ws[WS_POSC + b], s1);
    atomicAdd(&ws[WS_POSN + b], s2);
    atomicAdd(&ws[WS_PDIAG + b], s3);
    atomicAdd(&ws[WS_CROSS + b], s4);
    atomicAdd(&ws[WS_NEGS + b], s5);
  }
}

// ---------------- finalize ----------------
__global__ void finalize(const float* __restrict__ ws, const float* __restrict__ pcount,
                         float* __restrict__ out) {
  if (threadIdx.x != 0 || blockIdx.x != 0) return;
  const float coord = ws[WS_COORD] / 32768.f;
  const float reg   = ws[WS_REG] / 2097152.f;
  const float edge  = ws[WS_BCE] / 16777216.f;
  float cntl = 0.f, contra = 0.f;
  for (int b = 0; b < 16; ++b) {
    const float d = fabsf(pcount[b] - ws[WS_CNT + b]);
    cntl += (d < 1.f) ? 0.5f * d * d : d - 0.5f;
    const float posc = ws[WS_POSC + b];
    const float pos = (ws[WS_POSN + b] - 2.f * ws[WS_CROSS + b]) / fmaxf(posc, 1.f);
    const float negc = 1024.f * 1024.f - 1024.f - (posc - ws[WS_PDIAG + b]);
    const float neg = ws[WS_NEGS + b] / fmaxf(negc, 1.f);
    contra += pos + neg;
  }
  cntl *= (1.f / 16.f);
  contra *= (1.f / 16.f);
  const float total = coord + 2.f * edge + 0.1f * cntl + 0.001f * reg + 0.1f * contra;
  out[0] = total; out[1] = coord; out[2] = edge;
  out[3] = cntl;  out[4] = reg;   out[5] = contra;
}

extern "C" void kernel_launch(void* const* d_in, const int* in_sizes, int n_in,
                              void* d_out, int out_size, void* d_ws, size_t ws_size,
                              hipStream_t stream) {
  (void)in_sizes; (void)n_in; (void)out_size; (void)ws_size;
  const float* pcoord = (const float*)d_in[0];
  const float* pts    = (const float*)d_in[1];
  const float* logits = (const float*)d_in[2];
  const float* adj    = (const float*)d_in[3];
  const float* masks  = (const float*)d_in[4];
  const float* pcount = (const float*)d_in[5];
  const float* nf     = (const float*)d_in[6];
  float* ws  = (float*)d_ws;
  float* out = (float*)d_out;

  hipMemsetAsync(ws, 0, WS_NORM * sizeof(float), stream);
  prep<<<128, 256, 0, stream>>>(nf, pcoord, pts, masks, ws);
  fused_tiles<<<4096, 256, 0, stream>>>(logits, adj, nf, ws);
  finalize<<<1, 64, 0, stream>>>(ws, pcount, out);
}

// Round 4
// 216.277 us; speedup vs baseline: 1.2683x; 1.2511x over previous
//
#include <hip/hip_runtime.h>
#include <hip/hip_bf16.h>

#define NN 1024
#define DD 128
#define TS 64          // gram tile edge
#define PITCH 136      // bf16 elems per LDS feat row (128 + 8 pad)

// ws layout (floats)
#define WS_COORD 0
#define WS_REG   1
#define WS_BCE   2
#define WS_POSN  3     // [3,19)   per-batch  sum A*(ni+nj)
#define WS_POSC  19    // [19,35)  per-batch  count A>0.5
#define WS_NEGS  35    // [35,51)  per-batch  hinge^2 sum (rare)
#define WS_PDIAG 51    // [51,67)  per-batch  diag positives
#define WS_CROSS 67    // [67,83)  per-batch  sum A*G
#define WS_CNT   83    // [83,99)  per-batch  mask sums
#define WS_NORM  112   // [112, 112+16384) node norms n[b][i] (f32)

typedef __bf16 bf16_t;
typedef bf16_t bf16x8 __attribute__((ext_vector_type(8)));
typedef float  f32x4  __attribute__((ext_vector_type(4)));

// ---------------- kernel 0: norms + reg + coord + mask counts ----------------
__global__ __launch_bounds__(256) void prep(
    const float* __restrict__ feat, const float* __restrict__ pcoord,
    const float* __restrict__ pts,  const float* __restrict__ masks,
    float* __restrict__ ws) {
  __shared__ float red[4][3];
  const int bx = blockIdx.x;               // 128 blocks: 8 per batch
  const int b = bx >> 3, slab = bx & 7;
  const int t = threadIdx.x, lane = t & 63, w = t >> 6;
  const int sub = lane >> 4, lq = lane & 15;   // 4 nodes per wave, 16 lanes/node
  const float* fb = feat + (size_t)b * NN * DD;

  float reg = 0.f;
  #pragma unroll
  for (int it = 0; it < 8; ++it) {
    const int node = slab * 128 + it * 16 + w * 4 + sub;
    const float4* src = (const float4*)(fb + (size_t)node * DD) + lq * 2;
    float4 u = src[0], v = src[1];
    float s = u.x*u.x + u.y*u.y + u.z*u.z + u.w*u.w
            + v.x*v.x + v.y*v.y + v.z*v.z + v.w*v.w;
    s += __shfl_xor(s, 1); s += __shfl_xor(s, 2);
    s += __shfl_xor(s, 4); s += __shfl_xor(s, 8);
    if (lq == 0) { ws[WS_NORM + b * NN + node] = s; reg += s; }
  }
  const int ci = bx * 256 + t;
  const float d = pcoord[ci] - pts[ci];
  float coord = d * d;
  float cnt = (t < 128) ? masks[b * NN + slab * 128 + t] : 0.f;

  #pragma unroll
  for (int o = 32; o; o >>= 1) {
    coord += __shfl_xor(coord, o);
    reg   += __shfl_xor(reg, o);
    cnt   += __shfl_xor(cnt, o);
  }
  if (lane == 0) { red[w][0] = coord; red[w][1] = reg; red[w][2] = cnt; }
  __syncthreads();
  if (t == 0) {
    float c = 0.f, r = 0.f, n = 0.f;
    for (int i = 0; i < 4; ++i) { c += red[i][0]; r += red[i][1]; n += red[i][2]; }
    atomicAdd(&ws[WS_COORD], c);
    atomicAdd(&ws[WS_REG], r);
    atomicAdd(&ws[WS_CNT + b], n);
  }
}

// ---------------- mega kernel: interleaved stream blocks + gram blocks ----------------
// grid 6144: bx%3==0 -> stream (2048 blocks), else gram (4096 blocks).
// Stream path: NO barriers before the consume -> L/A loads never hit a vmcnt(0)
// drain; explicit Lb[8]/Ab[8] batch keeps 16 float4 in flight per thread.
// Gram path: one barrier total; A-tile frag loads issued BEFORE the stage
// barrier (they complete under the ~900cy stage phase, so the drain is free);
// consume straight from MFMA fragments (no gbuf, no second barrier).
__global__ __launch_bounds__(256, 4) void mega(
    const float* __restrict__ logits, const float* __restrict__ adj,
    const float* __restrict__ feat, float* __restrict__ ws) {
  __shared__ __align__(16) char smem[2 * TS * PITCH * sizeof(bf16_t)];  // 34816 B
  __shared__ float red[4][6];
  bf16_t* lsA = (bf16_t*)smem;
  bf16_t* lsB = (bf16_t*)(smem + TS * PITCH * sizeof(bf16_t));

  const int bx = blockIdx.x;
  const int sel = bx % 3;
  const int t = threadIdx.x, lane = t & 63, wave = t >> 6;

  if (sel == 0) {
    // ================= stream path: 8 rows x 1024 cols of L,A =================
    const int sid = bx / 3;                // 0..2047
    const int b = sid >> 7, rblk = sid & 127;
    const size_t base = ((size_t)b * NN + (size_t)rblk * 8) * NN;
    const float4* Lr = (const float4*)(logits + base);
    const float4* Ar = (const float4*)(adj + base);
    const float* nrm = ws + WS_NORM + b * NN;

    float4 Lb[8], Ab[8];
    #pragma unroll
    for (int r = 0; r < 8; ++r) Lb[r] = Lr[r * 256 + t];
    #pragma unroll
    for (int r = 0; r < 8; ++r) Ab[r] = Ar[r * 256 + t];
    const float4 nj = *(const float4*)(nrm + t * 4);
    float ni[8];
    #pragma unroll
    for (int r = 0; r < 8; ++r) ni[r] = nrm[rblk * 8 + r];

    float bce = 0.f, posc = 0.f, posn = 0.f, pdiag = 0.f;
    #pragma unroll
    for (int r = 0; r < 8; ++r) {
      const float4 L = Lb[r], A = Ab[r];
      bce += fmaxf(L.x, 0.f) - L.x * A.x + __logf(1.f + __expf(-fabsf(L.x)));
      bce += fmaxf(L.y, 0.f) - L.y * A.y + __logf(1.f + __expf(-fabsf(L.y)));
      bce += fmaxf(L.z, 0.f) - L.z * A.z + __logf(1.f + __expf(-fabsf(L.z)));
      bce += fmaxf(L.w, 0.f) - L.w * A.w + __logf(1.f + __expf(-fabsf(L.w)));
      const float px = (A.x > 0.5f) ? 1.f : 0.f;
      const float py = (A.y > 0.5f) ? 1.f : 0.f;
      const float pz = (A.z > 0.5f) ? 1.f : 0.f;
      const float pw = (A.w > 0.5f) ? 1.f : 0.f;
      posc += px + py + pz + pw;
      posn += px * (ni[r] + nj.x) + py * (ni[r] + nj.y)
            + pz * (ni[r] + nj.z) + pw * (ni[r] + nj.w);
      const int grow = rblk * 8 + r;
      if ((grow >> 2) == t) {              // diagonal element lives here
        const int e = grow & 3;
        const float av = (e == 0) ? A.x : (e == 1) ? A.y : (e == 2) ? A.z : A.w;
        if (av > 0.5f) pdiag += 1.f;
      }
    }
    #pragma unroll
    for (int o = 32; o; o >>= 1) {
      bce   += __shfl_xor(bce, o);
      posc  += __shfl_xor(posc, o);
      posn  += __shfl_xor(posn, o);
      pdiag += __shfl_xor(pdiag, o);
    }
    if (lane == 0) {
      red[wave][0] = bce; red[wave][1] = posc;
      red[wave][2] = posn; red[wave][3] = pdiag;
    }
    __syncthreads();
    if (t == 0) {
      float s0 = 0.f, s1 = 0.f, s2 = 0.f, s3 = 0.f;
      for (int i = 0; i < 4; ++i) {
        s0 += red[i][0]; s1 += red[i][1]; s2 += red[i][2]; s3 += red[i][3];
      }
      atomicAdd(&ws[WS_BCE], s0);
      atomicAdd(&ws[WS_POSC + b], s1);
      atomicAdd(&ws[WS_POSN + b], s2);
      atomicAdd(&ws[WS_PDIAG + b], s3);
    }
    return;
  }

  // ================= gram path: 64x64 tile, cross + neg safety =================
  const int gid = (bx / 3) * 2 + (sel - 1);     // 0..4095
  const int bm = ((gid & 7) << 9) | (gid >> 3); // XCD swizzle: 2 batches / XCD
  const int b = bm >> 8, tid = bm & 255;
  const int ti = (tid >> 4) << 6, tj = (tid & 15) << 6;
  const int lrow = lane & 15, quad = lane >> 4;
  const float* fb = feat + (size_t)b * NN * DD;
  const float* nrm = ws + WS_NORM + b * NN;

  // A-tile in fragment layout + norms: issued first; complete under stage phase.
  const int rbase = wave * 16 + quad * 4;       // fragment row base within tile
  const int grow0 = ti + rbase;
  const float* ap = adj + (size_t)b * NN * NN + (size_t)grow0 * NN + (tj + lrow);
  float Af[4][4];                               // [fc][r]
  #pragma unroll
  for (int r = 0; r < 4; ++r)
    #pragma unroll
    for (int fc = 0; fc < 4; ++fc)
      Af[fc][r] = ap[(size_t)r * NN + fc * 16];
  const float4 niv = *(const float4*)(nrm + grow0);
  float njv[4];
  #pragma unroll
  for (int fc = 0; fc < 4; ++fc) njv[fc] = nrm[tj + fc * 16 + lrow];

  // stage feat tiles (A rows [ti,ti+64), B rows [tj,tj+64)) as bf16; L2-hot
  #pragma unroll
  for (int it = 0; it < 8; ++it) {
    const int cid = it * 256 + t;
    const int tile = cid >> 10;
    const int sub = cid & 1023;
    const int row = sub >> 4;
    const int c8 = sub & 15;
    const float* src = fb + (size_t)((tile ? tj : ti) + row) * DD + c8 * 8;
    const float4 u = *(const float4*)src;
    const float4 v = *(const float4*)(src + 4);
    bf16x8 pk;
    pk[0]=(bf16_t)u.x; pk[1]=(bf16_t)u.y; pk[2]=(bf16_t)u.z; pk[3]=(bf16_t)u.w;
    pk[4]=(bf16_t)v.x; pk[5]=(bf16_t)v.y; pk[6]=(bf16_t)v.z; pk[7]=(bf16_t)v.w;
    *(bf16x8*)((tile ? lsB : lsA) + row * PITCH + c8 * 8) = pk;
  }
  __syncthreads();

  // MFMA Gram: wave w rows [w*16,w*16+16) x 64 cols
  f32x4 acc[4];
  #pragma unroll
  for (int fc = 0; fc < 4; ++fc) acc[fc] = (f32x4){0.f, 0.f, 0.f, 0.f};
  #pragma unroll
  for (int k0 = 0; k0 < DD; k0 += 32) {
    const int kc = k0 + quad * 8;
    const bf16x8 aF = *(const bf16x8*)&lsA[(wave * 16 + lrow) * PITCH + kc];
    #pragma unroll
    for (int fc = 0; fc < 4; ++fc) {
      const bf16x8 bF = *(const bf16x8*)&lsB[(fc * 16 + lrow) * PITCH + kc];
      acc[fc] = __builtin_amdgcn_mfma_f32_16x16x32_bf16(aF, bF, acc[fc], 0, 0, 0);
    }
  }

  // consume straight from fragments: no gbuf, no second barrier
  float cross = 0.f, negs = 0.f;
  #pragma unroll
  for (int fc = 0; fc < 4; ++fc) {
    const int gcol = tj + fc * 16 + lrow;
    #pragma unroll
    for (int r = 0; r < 4; ++r) {
      const float a = Af[fc][r];
      const float g = acc[fc][r];
      if (a > 0.5f) {
        cross += g;
      } else {
        const int grow = grow0 + r;
        const float ni = (r == 0) ? niv.x : (r == 1) ? niv.y : (r == 2) ? niv.z : niv.w;
        const float sq = ni + njv[fc] - 2.f * g;
        if (sq < 1.f && grow != gcol) {    // essentially never for these inputs
          const float dd = sqrtf(fmaxf(sq, 1e-12f));
          const float h = 1.f - dd;
          negs += h * h;
        }
      }
    }
  }
  #pragma unroll
  for (int o = 32; o; o >>= 1) {
    cross += __shfl_xor(cross, o);
    negs  += __shfl_xor(negs, o);
  }
  if (lane == 0) { red[wave][0] = cross; red[wave][1] = negs; }
  __syncthreads();
  if (t == 0) {
    float s0 = 0.f, s1 = 0.f;
    for (int i = 0; i < 4; ++i) { s0 += red[i][0]; s1 += red[i][1]; }
    atomicAdd(&ws[WS_CROSS + b], s0);
    atomicAdd(&ws[WS_NEGS + b], s1);
  }
}

// ---------------- finalize ----------------
__global__ void finalize(const float* __restrict__ ws, const float* __restrict__ pcount,
                         float* __restrict__ out) {
  if (threadIdx.x != 0 || blockIdx.x != 0) return;
  const float coord = ws[WS_COORD] / 32768.f;
  const float reg   = ws[WS_REG] / 2097152.f;
  const float edge  = ws[WS_BCE] / 16777216.f;
  float cntl = 0.f, contra = 0.f;
  for (int b = 0; b < 16; ++b) {
    const float d = fabsf(pcount[b] - ws[WS_CNT + b]);
    cntl += (d < 1.f) ? 0.5f * d * d : d - 0.5f;
    const float posc = ws[WS_POSC + b];
    const float pos = (ws[WS_POSN + b] - 2.f * ws[WS_CROSS + b]) / fmaxf(posc, 1.f);
    const float negc = 1024.f * 1024.f - 1024.f - (posc - ws[WS_PDIAG + b]);
    const float neg = ws[WS_NEGS + b] / fmaxf(negc, 1.f);
    contra += pos + neg;
  }
  cntl *= (1.f / 16.f);
  contra *= (1.f / 16.f);
  const float total = coord + 2.f * edge + 0.1f * cntl + 0.001f * reg + 0.1f * contra;
  out[0] = total; out[1] = coord; out[2] = edge;
  out[3] = cntl;  out[4] = reg;   out[5] = contra;
}

extern "C" void kernel_launch(void* const* d_in, const int* in_sizes, int n_in,
                              void* d_out, int out_size, void* d_ws, size_t ws_size,
                              hipStream_t stream) {
  (void)in_sizes; (void)n_in; (void)out_size; (void)ws_size;
  const float* pcoord = (const float*)d_in[0];
  const float* pts    = (const float*)d_in[1];
  const float* logits = (const float*)d_in[2];
  const float* adj    = (const float*)d_in[3];
  const float* masks  = (const float*)d_in[4];
  const float* pcount = (const float*)d_in[5];
  const float* nf     = (const float*)d_in[6];
  float* ws  = (float*)d_ws;
  float* out = (float*)d_out;

  hipMemsetAsync(ws, 0, WS_NORM * sizeof(float), stream);
  prep<<<128, 256, 0, stream>>>(nf, pcoord, pts, masks, ws);
  mega<<<6144, 256, 0, stream>>>(logits, adj, nf, ws);
  finalize<<<1, 64, 0, stream>>>(ws, pcount, out);
}